// Round 1
// baseline (480.168 us; speedup 1.0000x reference)
//
#include <hip/hip_runtime.h>

// Nearest-prototype argmin: N=500k, K=256, D=64, fp32.
// d2 = (x_sq - 2*dot(x,mu)) + mu_sq, argmin over K, first-min-wins.
// Strategy: fp32 VALU (no fp32 MFMA on CDNA4). x in VGPRs, mus staged in LDS
// in two 32KB chunks (keeps ~4 blocks/CU). LDS reads are wave-uniform ->
// broadcast, conflict-free.

#define KPROTO 256
#define DIM 64
#define KCHUNK 128  // protos per LDS chunk (32 KB)

__global__ void musq_kernel(const float* __restrict__ mus,
                            float* __restrict__ musq) {
    int k = threadIdx.x;  // one block of 256
    const float4* m4 = (const float4*)(mus + k * DIM);
    float a0 = 0.f, a1 = 0.f, a2 = 0.f, a3 = 0.f;
#pragma unroll
    for (int q = 0; q < DIM / 4; ++q) {
        float4 v = m4[q];
        a0 += v.x * v.x;
        a1 += v.y * v.y;
        a2 += v.z * v.z;
        a3 += v.w * v.w;
    }
    musq[k] = (a0 + a1) + (a2 + a3);
}

__launch_bounds__(256, 4)
__global__ void argmin_kernel(const float* __restrict__ X,
                              const float* __restrict__ mus,
                              const float* __restrict__ musq,
                              int* __restrict__ out, int n) {
    __shared__ float s_mu[KCHUNK * DIM];   // 32 KB
    __shared__ float s_musq[KPROTO];       // 1 KB

    const int tid = threadIdx.x;
    const int i = blockIdx.x * 256 + tid;
    const int iread = (i < n) ? i : (n - 1);  // OOB lanes compute garbage, no store

    s_musq[tid] = musq[tid];

    // x -> 64 VGPRs via 16x float4
    float4 xv[DIM / 4];
    const float4* xp = (const float4*)(X + (size_t)iread * DIM);
#pragma unroll
    for (int q = 0; q < DIM / 4; ++q) xv[q] = xp[q];

    // x_sq, multi-accumulator like the dot below
    float a0 = 0.f, a1 = 0.f, a2 = 0.f, a3 = 0.f;
#pragma unroll
    for (int q = 0; q < DIM / 4; ++q) {
        float4 v = xv[q];
        a0 += v.x * v.x;
        a1 += v.y * v.y;
        a2 += v.z * v.z;
        a3 += v.w * v.w;
    }
    const float x_sq = (a0 + a1) + (a2 + a3);

    float best = 3.4e38f;
    int bidx = 0;

    for (int kc = 0; kc < KPROTO / KCHUNK; ++kc) {
        __syncthreads();  // protect previous chunk from overwrite
        // stage KCHUNK protos: 8192 floats = 2048 float4, 256 threads x 8
        const float4* src = (const float4*)(mus + kc * KCHUNK * DIM);
        float4* dst = (float4*)s_mu;
#pragma unroll
        for (int t = 0; t < (KCHUNK * DIM / 4) / 256; ++t)
            dst[tid + t * 256] = src[tid + t * 256];
        __syncthreads();

        for (int kk = 0; kk < KCHUNK; ++kk) {
            const float4* m4 = (const float4*)(s_mu + kk * DIM);
            float b0 = 0.f, b1 = 0.f, b2 = 0.f, b3 = 0.f;
#pragma unroll
            for (int q = 0; q < DIM / 4; ++q) {
                float4 mv = m4[q];  // wave-uniform addr -> LDS broadcast
                float4 xq = xv[q];
                b0 += xq.x * mv.x;
                b1 += xq.y * mv.y;
                b2 += xq.z * mv.z;
                b3 += xq.w * mv.w;
            }
            const float dot = (b0 + b1) + (b2 + b3);
            const int k = kc * KCHUNK + kk;
            // mirror np rounding: (x_sq - 2*dot) then + mu_sq
            const float d2 = (x_sq - 2.0f * dot) + s_musq[k];
            if (d2 < best) {  // strict <: first minimum wins (np.argmin)
                best = d2;
                bidx = k;
            }
        }
    }

    if (i < n) out[i] = bidx;
}

extern "C" void kernel_launch(void* const* d_in, const int* in_sizes, int n_in,
                              void* d_out, int out_size, void* d_ws, size_t ws_size,
                              hipStream_t stream) {
    const float* X = (const float*)d_in[0];
    const float* mus = (const float*)d_in[1];
    int* out = (int*)d_out;
    float* musq = (float*)d_ws;  // 256 floats

    const int n = in_sizes[0] / DIM;  // 500000

    musq_kernel<<<1, KPROTO, 0, stream>>>(mus, musq);

    const int grid = (n + 255) / 256;
    argmin_kernel<<<grid, 256, 0, stream>>>(X, mus, musq, out, n);
}

// Round 2
// 260.695 us; speedup vs baseline: 1.8419x; 1.8419x over previous
//
#include <hip/hip_runtime.h>

// Nearest-prototype argmin: N=500k, K=256, D=64, fp32.
// R2: mus are wave-uniform -> load them into SGPRs via inline-asm
// s_load_dwordx16 (scalar pipe), FMA with SGPR operand. Removes the LDS
// pipe from the inner loop entirely (R1 was LDS-BW-bound: 32.7 TB of
// per-lane LDS reads ~= 500 us roofline). x pinned in 16 named float4 regs.

#define KPROTO 256
#define DIM 64

typedef __attribute__((ext_vector_type(16))) float f32x16;

__global__ void musq_kernel(const float* __restrict__ mus,
                            float* __restrict__ musq) {
    int k = threadIdx.x;  // one block of 256
    const float4* m4 = (const float4*)(mus + k * DIM);
    float a0 = 0.f, a1 = 0.f, a2 = 0.f, a3 = 0.f;
#pragma unroll
    for (int q = 0; q < DIM / 4; ++q) {
        float4 v = m4[q];
        a0 = fmaf(v.x, v.x, a0);
        a1 = fmaf(v.y, v.y, a1);
        a2 = fmaf(v.z, v.z, a2);
        a3 = fmaf(v.w, v.w, a3);
    }
    musq[k] = (a0 + a1) + (a2 + a3);
}

// b0 accumulates component .x of each dim-group in order, b1 -> .y, etc.
// Same accumulation order as the R1 kernel that passed with absmax=0.
#define FMA16(m, p, q, r, s)                                            \
    b0 = fmaf(m[0],  p.x, b0); b1 = fmaf(m[1],  p.y, b1);               \
    b2 = fmaf(m[2],  p.z, b2); b3 = fmaf(m[3],  p.w, b3);               \
    b0 = fmaf(m[4],  q.x, b0); b1 = fmaf(m[5],  q.y, b1);               \
    b2 = fmaf(m[6],  q.z, b2); b3 = fmaf(m[7],  q.w, b3);               \
    b0 = fmaf(m[8],  r.x, b0); b1 = fmaf(m[9],  r.y, b1);               \
    b2 = fmaf(m[10], r.z, b2); b3 = fmaf(m[11], r.w, b3);               \
    b0 = fmaf(m[12], s.x, b0); b1 = fmaf(m[13], s.y, b1);               \
    b2 = fmaf(m[14], s.z, b2); b3 = fmaf(m[15], s.w, b3);

__launch_bounds__(256, 4)
__global__ void argmin_kernel(const float* __restrict__ X,
                              const float* __restrict__ mus,
                              const float* __restrict__ musq,
                              int* __restrict__ out, int n) {
    const int i = blockIdx.x * 256 + threadIdx.x;
    const int iread = (i < n) ? i : (n - 1);  // OOB lanes compute, don't store

    // x -> 64 named VGPRs (named scalars so the allocator cannot demote)
    const float4* xp = (const float4*)(X + (size_t)iread * DIM);
    const float4 x0 = xp[0],  x1 = xp[1],  x2 = xp[2],  x3 = xp[3];
    const float4 x4 = xp[4],  x5 = xp[5],  x6 = xp[6],  x7 = xp[7];
    const float4 x8 = xp[8],  x9 = xp[9],  x10 = xp[10], x11 = xp[11];
    const float4 x12 = xp[12], x13 = xp[13], x14 = xp[14], x15 = xp[15];

    float a0 = 0.f, a1 = 0.f, a2 = 0.f, a3 = 0.f;
#define XSQ(v) a0 = fmaf(v.x, v.x, a0); a1 = fmaf(v.y, v.y, a1); \
               a2 = fmaf(v.z, v.z, a2); a3 = fmaf(v.w, v.w, a3);
    XSQ(x0) XSQ(x1) XSQ(x2) XSQ(x3) XSQ(x4) XSQ(x5) XSQ(x6) XSQ(x7)
    XSQ(x8) XSQ(x9) XSQ(x10) XSQ(x11) XSQ(x12) XSQ(x13) XSQ(x14) XSQ(x15)
#undef XSQ
    const float x_sq = (a0 + a1) + (a2 + a3);

    float best = 3.4e38f;
    int bidx = 0;

    const float* mk = mus;   // uniform -> SGPR pair
    const float* qk = musq;  // uniform -> SGPR pair

    for (int k = 0; k < KPROTO; ++k) {
        f32x16 m0, m1, m2, m3;
        float msq;
        // 64 mu floats + mu_sq -> SGPRs through the scalar pipe.
        asm volatile(
            "s_load_dwordx16 %0, %5, 0\n\t"
            "s_load_dwordx16 %1, %5, 64\n\t"
            "s_load_dwordx16 %2, %5, 128\n\t"
            "s_load_dwordx16 %3, %5, 192\n\t"
            "s_load_dword    %4, %6, 0\n\t"
            "s_waitcnt lgkmcnt(0)"
            : "=&s"(m0), "=&s"(m1), "=&s"(m2), "=&s"(m3), "=&s"(msq)
            : "s"(mk), "s"(qk));

        float b0 = 0.f, b1 = 0.f, b2 = 0.f, b3 = 0.f;
        FMA16(m0, x0,  x1,  x2,  x3)    // dims  0..15
        FMA16(m1, x4,  x5,  x6,  x7)    // dims 16..31
        FMA16(m2, x8,  x9,  x10, x11)   // dims 32..47
        FMA16(m3, x12, x13, x14, x15)   // dims 48..63

        const float dot = (b0 + b1) + (b2 + b3);
        // mirror np rounding: (x_sq - 2*dot) then + mu_sq (2*dot is exact)
        const float d2 = (x_sq - 2.0f * dot) + msq;
        if (d2 < best) {  // strict <: first minimum wins (np.argmin)
            best = d2;
            bidx = k;
        }

        mk += DIM;
        qk += 1;
    }

    if (i < n) out[i] = bidx;
}

extern "C" void kernel_launch(void* const* d_in, const int* in_sizes, int n_in,
                              void* d_out, int out_size, void* d_ws, size_t ws_size,
                              hipStream_t stream) {
    const float* X = (const float*)d_in[0];
    const float* mus = (const float*)d_in[1];
    int* out = (int*)d_out;
    float* musq = (float*)d_ws;  // 256 floats of scratch

    const int n = in_sizes[0] / DIM;  // 500000

    musq_kernel<<<1, KPROTO, 0, stream>>>(mus, musq);

    const int grid = (n + 255) / 256;
    argmin_kernel<<<grid, 256, 0, stream>>>(X, mus, musq, out, n);
}